// Round 4
// baseline (386.684 us; speedup 1.0000x reference)
//
#include <hip/hip_runtime.h>
#include <hip/hip_bf16.h>

// Problem constants
#define B_ROWS 16384
#define IN_DIM 1280
#define BELLY  1024
#define SCALE  512
#define NBINS  100
#define NPTOT  1000   // NBINS*NPAT

typedef __attribute__((ext_vector_type(8))) short short8_t;
typedef __attribute__((ext_vector_type(4))) float f32x4;

// ---------- helpers ----------
__device__ __forceinline__ unsigned short f2bf(float f) {
  union { float f; unsigned int u; } v; v.f = f;
  unsigned int r = v.u + 0x7FFFu + ((v.u >> 16) & 1u);  // RNE
  return (unsigned short)(r >> 16);
}

__device__ __forceinline__ void gload16(const void* g, void* l) {
  __builtin_amdgcn_global_load_lds(
      (const __attribute__((address_space(1))) unsigned int*)g,
      (__attribute__((address_space(3))) unsigned int*)l, 16, 0, 0);
}

// ---------- transpose + convert: in f32 [K][N] -> out bf16 [Npad][K], zero-pad rows >= N ----------
__global__ void transpose_cvt(const float* __restrict__ in,
                              unsigned short* __restrict__ out,
                              int K, int N, int Npad) {
  __shared__ float tile[32][33];
  int k0 = blockIdx.x * 32;
  int n0 = blockIdx.y * 32;
  int tx = threadIdx.x, ty = threadIdx.y;  // 32 x 8
  #pragma unroll
  for (int r = 0; r < 32; r += 8) {
    int k = k0 + ty + r, n = n0 + tx;
    tile[ty + r][tx] = (k < K && n < N) ? in[(size_t)k * N + n] : 0.0f;
  }
  __syncthreads();
  #pragma unroll
  for (int r = 0; r < 32; r += 8) {
    int n = n0 + ty + r, k = k0 + tx;
    if (n < Npad && k < K) out[(size_t)n * K + k] = f2bf(tile[tx][ty + r]);
  }
}

// ---------- timestep class + global max ----------
__global__ void tclass_kernel(const int* __restrict__ ts, float* __restrict__ outc,
                              int* __restrict__ gmax, int n) {
  __shared__ int smax;
  if (threadIdx.x == 0) smax = 0;
  __syncthreads();
  int local = 0;
  for (int i = blockIdx.x * blockDim.x + threadIdx.x; i < n;
       i += gridDim.x * blockDim.x) {
    float v = (float)ts[i] / 1000.0f * 100.0f;
    int c = (int)v;
    c = min(max(c, 0), NBINS - 1);
    outc[i] = (float)c;
    local = max(local, c);
  }
  atomicMax(&smax, local);
  __syncthreads();
  if (threadIdx.x == 0) atomicMax(gmax, smax);
}

// ================= 256x256 8-phase GEMM (T2+T3+T4+T5) =================
// C[M,N] = A[M,K] * Bt[N,K]^T. BM=BN=256, BK=64, 8 waves (2Mx4N).
// AF32=false: A bf16 via gload_lds (linear LDS dest + inverse-swizzled global src).
// AF32=true : A f32 reg-staged (linear global src, f2bf, ds_write to swizzled dest);
//             A-loads issued 3 phases ahead (prologue/P3/P7), drained vmcnt(0) in
//             AWRITE at P2/P6. B path unchanged.
// ds_read side: byte ^= (row&7)<<4 slot-XOR on both A and B (2-way residual = free).
// EPI 0: +bias, relu -> bf16 outH ; EPI 1: f32 outF ;
// EPI 2: dual-region (fused GEMM3+4): col<1000 -> outF (+bias), col in
//        [1024,1124) -> outF2 (+bias2).
template<int K, int EPI, bool AF32>
__global__ __launch_bounds__(512, 1)
void gemm256(const void* __restrict__ Av,
             const unsigned short* __restrict__ Bt,
             float* __restrict__ outF, unsigned short* __restrict__ outH,
             const float* __restrict__ bias,
             float* __restrict__ outF2, const float* __restrict__ bias2,
             int ldOut) {
  __shared__ __align__(16) unsigned short lds[65536];  // 128 KiB
  constexpr int NT = K / 64;
  static_assert(NT % 2 == 0, "NT must be even");
  const int tid  = threadIdx.x;
  const int wid  = tid >> 6;
  const int lane = tid & 63;
  const int r0 = blockIdx.x * 256;
  const int c0 = blockIdx.y * 256;

  const int srow = wid * 16 + (lane >> 3);
  const int scol = (((lane & 7) ^ (lane >> 3)) << 3);   // elems, inverse-swizzled
  const unsigned short* gB = Bt + (size_t)(c0 + srow) * K + scol;
  const unsigned short* gA16 = AF32 ? nullptr
      : (const unsigned short*)Av + (size_t)(r0 + srow) * K + scol;
  const float* gAf = AF32
      ? (const float*)Av + (size_t)(r0 + wid * 16 + (lane >> 3)) * K + (lane & 7) * 8
      : nullptr;
  const int sdst = wid * 1024;                          // elem offset of wave chunk
  const int swzslot = (lane & 7) ^ (lane >> 3);         // ds_write dest slot (AF32)

  const int fr = lane & 15;
  const int Ah = wid >> 2;            // this wave's A half (row block)
  const int wc = (wid & 3) * 64;      // wave col offset in 256-wide tile
  const int ca0 = ((((lane >> 4) << 4) +  0) ^ ((lane & 7) << 4)) >> 1;
  const int ca1 = ((((lane >> 4) << 4) + 64) ^ ((lane & 7) << 4)) >> 1;

  f32x4 acc[8][4] = {};
  short8_t af[4][2];        // A frags: one m-half x 2 k-slices
  short8_t bfr[2][2][2];    // B frags: [nh][nn][ks]
  float av[2][2][8];        // AF32 in-flight A (2 halves x 2 row-groups x 8 f32)

#define STAGEB_(buf, half, kt) do {                                            \
    const unsigned short* g_ = gB                                              \
        + (size_t)(half) * 128 * K + (size_t)(kt) * 64;                        \
    unsigned short* l_ = &lds[(buf) * 32768 + 16384 + (half) * 8192 + sdst];   \
    gload16(g_, l_);                                                           \
    gload16(g_ + 8 * K, l_ + 512);                                             \
  } while (0)

#define STAGEA16_(buf, half, kt) do {                                          \
    const unsigned short* g_ = gA16                                            \
        + (size_t)(half) * 128 * K + (size_t)(kt) * 64;                        \
    unsigned short* l_ = &lds[(buf) * 32768 + (half) * 8192 + sdst];           \
    gload16(g_, l_);                                                           \
    gload16(g_ + 8 * K, l_ + 512);                                             \
  } while (0)

#define ALOAD_(kt) do {                                                        \
    _Pragma("unroll")                                                          \
    for (int h_ = 0; h_ < 2; ++h_)                                             \
      _Pragma("unroll")                                                        \
      for (int j_ = 0; j_ < 2; ++j_) {                                         \
        const float* p_ = gAf + (size_t)(h_ * 128 + j_ * 8) * K + (size_t)(kt) * 64; \
        *(float4*)&av[h_][j_][0] = ((const float4*)p_)[0];                     \
        *(float4*)&av[h_][j_][4] = ((const float4*)p_)[1];                     \
      } } while (0)

#define AWRITE_(buf) do {                                                      \
    asm volatile("s_waitcnt vmcnt(0)" ::: "memory");                           \
    _Pragma("unroll")                                                          \
    for (int h_ = 0; h_ < 2; ++h_)                                             \
      _Pragma("unroll")                                                        \
      for (int j_ = 0; j_ < 2; ++j_) {                                         \
        union { short8_t v; unsigned short u[8]; } t_;                         \
        _Pragma("unroll")                                                      \
        for (int e_ = 0; e_ < 8; ++e_) t_.u[e_] = f2bf(av[h_][j_][e_]);        \
        *(short8_t*)&lds[(buf) * 32768 + h_ * 8192 + sdst                      \
                         + (lane >> 3) * 64 + j_ * 512 + swzslot * 8] = t_.v;  \
      } } while (0)

#define LDA_(buf, mh) do {                                                     \
    const unsigned short* ab_ = &lds[(buf) * 32768 + Ah * 8192];               \
    _Pragma("unroll")                                                          \
    for (int mm = 0; mm < 4; ++mm) {                                           \
      int rwh_ = (mh) * 64 + mm * 16 + fr;                                     \
      af[mm][0] = *(const short8_t*)&ab_[rwh_ * 64 + ca0];                     \
      af[mm][1] = *(const short8_t*)&ab_[rwh_ * 64 + ca1];                     \
    } } while (0)

#define LDB_(buf, nh) do {                                                     \
    _Pragma("unroll")                                                          \
    for (int nn = 0; nn < 2; ++nn) {                                           \
      int brow_ = wc + ((nh) * 2 + nn) * 16;                                   \
      const unsigned short* bb_ = &lds[(buf) * 32768 + 16384 + (brow_ >> 7) * 8192]; \
      int rwh_ = (brow_ & 127) + fr;                                           \
      bfr[nh][nn][0] = *(const short8_t*)&bb_[rwh_ * 64 + ca0];                \
      bfr[nh][nn][1] = *(const short8_t*)&bb_[rwh_ * 64 + ca1];                \
    } } while (0)

#define MM_(mh, nh) do {                                                       \
    _Pragma("unroll")                                                          \
    for (int mm = 0; mm < 4; ++mm)                                             \
      _Pragma("unroll")                                                        \
      for (int nn = 0; nn < 2; ++nn) {                                         \
        acc[(mh)*4+mm][(nh)*2+nn] = __builtin_amdgcn_mfma_f32_16x16x32_bf16(   \
            af[mm][0], bfr[nh][nn][0], acc[(mh)*4+mm][(nh)*2+nn], 0, 0, 0);    \
        acc[(mh)*4+mm][(nh)*2+nn] = __builtin_amdgcn_mfma_f32_16x16x32_bf16(   \
            af[mm][1], bfr[nh][nn][1], acc[(mh)*4+mm][(nh)*2+nn], 0, 0, 0);    \
      } } while (0)

#define BAR_       __builtin_amdgcn_s_barrier()
#define LGKM0_     asm volatile("s_waitcnt lgkmcnt(0)")
#define VM4_       asm volatile("s_waitcnt vmcnt(4)" ::: "memory")
#define PRIO1_     __builtin_amdgcn_s_setprio(1)
#define PRIO0_     __builtin_amdgcn_s_setprio(0)

  // ---- prologue
  if constexpr (AF32) {
    ALOAD_(0);
    STAGEB_(0, 0, 0); STAGEB_(0, 1, 0);
    STAGEB_(1, 0, 1); STAGEB_(1, 1, 1);
    AWRITE_(0);                 // vmcnt(0): A(0) regs + all B landed
    ALOAD_(1);                  // A(1), written at P2 of iter 0
    LGKM0_;
    BAR_;
  } else {
    STAGEB_(0, 0, 0); STAGEB_(0, 1, 0);
    STAGEA16_(0, 0, 0); STAGEA16_(0, 1, 0);
    STAGEB_(1, 0, 1); STAGEB_(1, 1, 1);
    VM4_;
    BAR_;
  }

  for (int t = 0; t < NT; t += 2) {
    const int t2 = (t + 2) % NT;       // mod: tail stages garbage, never consumed
    const int t3 = (t + 3) % NT;
    if constexpr (AF32) {
      // P1
      LDA_(0, 0); LDB_(0, 0);
      BAR_; LGKM0_; PRIO1_; MM_(0, 0); PRIO0_; BAR_;
      // P2: write A(t+1) into buf1 (regs loaded at prev P7 / prologue)
      LDB_(0, 1); AWRITE_(1);
      BAR_; LGKM0_; PRIO1_; MM_(0, 1); PRIO0_; BAR_;
      // P3: issue A(t+2) loads
      LDA_(0, 1); STAGEB_(0, 0, t2); ALOAD_(t2);
      BAR_; LGKM0_; PRIO1_; MM_(1, 0); PRIO0_; BAR_;
      // P4
      STAGEB_(0, 1, t2);
      BAR_; LGKM0_; PRIO1_; MM_(1, 1); PRIO0_; BAR_;
      // P5
      LDA_(1, 0); LDB_(1, 0);
      BAR_; LGKM0_; PRIO1_; MM_(0, 0); PRIO0_; BAR_;
      // P6: write A(t+2) into buf0
      LDB_(1, 1); AWRITE_(0);
      BAR_; LGKM0_; PRIO1_; MM_(0, 1); PRIO0_; BAR_;
      // P7: issue A(t+3) loads (garbage on final iter, never written)
      LDA_(1, 1); STAGEB_(1, 0, t3); ALOAD_(t3);
      BAR_; LGKM0_; PRIO1_; MM_(1, 0); PRIO0_; BAR_;
      // P8
      STAGEB_(1, 1, t3);
      BAR_; LGKM0_; PRIO1_; MM_(1, 1); PRIO0_; BAR_;
    } else {
      // P1
      LDA_(0, 0); LDB_(0, 0); STAGEA16_(1, 0, t + 1);
      BAR_; LGKM0_; PRIO1_; MM_(0, 0); PRIO0_; BAR_;
      // P2
      LDB_(0, 1); STAGEA16_(1, 1, t + 1);
      BAR_; LGKM0_; PRIO1_; MM_(0, 1); PRIO0_; BAR_;
      // P3
      LDA_(0, 1); STAGEB_(0, 0, t2);
      BAR_; LGKM0_; PRIO1_; MM_(1, 0); PRIO0_; BAR_;
      // P4
      STAGEB_(0, 1, t2); VM4_;
      BAR_; LGKM0_; PRIO1_; MM_(1, 1); PRIO0_; BAR_;
      // P5
      LDA_(1, 0); LDB_(1, 0); STAGEA16_(0, 0, t2);
      BAR_; LGKM0_; PRIO1_; MM_(0, 0); PRIO0_; BAR_;
      // P6
      LDB_(1, 1); STAGEA16_(0, 1, t2);
      BAR_; LGKM0_; PRIO1_; MM_(0, 1); PRIO0_; BAR_;
      // P7
      LDA_(1, 1); STAGEB_(1, 0, t3);
      BAR_; LGKM0_; PRIO1_; MM_(1, 0); PRIO0_; BAR_;
      // P8
      STAGEB_(1, 1, t3); VM4_;
      BAR_; LGKM0_; PRIO1_; MM_(1, 1); PRIO0_; BAR_;
    }
  }

  // drain stray (garbage) gload_lds / A-loads before LDS could be reused
  asm volatile("s_waitcnt vmcnt(0)" ::: "memory");

  const int orow = (lane >> 4) * 4;
  const int wrr  = (wid >> 2) * 128;
  #pragma unroll
  for (int m = 0; m < 8; ++m) {
    #pragma unroll
    for (int n = 0; n < 4; ++n) {
      #pragma unroll
      for (int i = 0; i < 4; ++i) {
        int row = r0 + wrr + m * 16 + orow + i;
        int col = c0 + wc + n * 16 + fr;
        float v = acc[m][n][i];
        if (EPI == 0) {
          v += bias[col];
          v = fmaxf(v, 0.0f);
          outH[(size_t)row * ldOut + col] = f2bf(v);
        } else if (EPI == 1) {
          outF[(size_t)row * ldOut + col] = v;
        } else {
          if (col < NPTOT) {
            outF[(size_t)row * ldOut + col] = v + bias[col];
          } else if (col >= 1024) {
            int cc = col - 1024;
            if (cc < NBINS) outF2[(size_t)row * NBINS + cc] = v + bias2[cc];
          }
        }
      }
    }
  }
#undef STAGEB_
#undef STAGEA16_
#undef ALOAD_
#undef AWRITE_
#undef LDA_
#undef LDB_
#undef MM_
}

// ---------- fused row-normalize + cantor ----------
__global__ void norm_cantor_kernel(const float* __restrict__ zraw,
                                   float* __restrict__ zout,
                                   unsigned short* __restrict__ zb,
                                   const float* __restrict__ w_pos,
                                   const float* __restrict__ b_pos,
                                   const float* __restrict__ alpha_p,
                                   const float* __restrict__ tclassf,
                                   const int* __restrict__ gmax,
                                   float* __restrict__ cv_out) {
  int wid = threadIdx.x >> 6, lane = threadIdx.x & 63;
  int row = blockIdx.x * 4 + wid;
  const float4* zr = (const float4*)(zraw + (size_t)row * SCALE);
  const float4* wp = (const float4*)w_pos;
  float4 v0 = zr[lane];
  float4 v1 = zr[lane + 64];
  float4 c0 = wp[lane];
  float4 c1 = wp[lane + 64];
  float ss = v0.x * v0.x + v0.y * v0.y + v0.z * v0.z + v0.w * v0.w
           + v1.x * v1.x + v1.y * v1.y + v1.z * v1.z + v1.w * v1.w;
  float rd = v0.x * c0.x + v0.y * c0.y + v0.z * c0.z + v0.w * c0.w
           + v1.x * c1.x + v1.y * c1.y + v1.z * c1.z + v1.w * c1.w;
  #pragma unroll
  for (int off = 1; off < 64; off <<= 1) {
    ss += __shfl_xor(ss, off);
    rd += __shfl_xor(rd, off);
  }
  float scale = 1.0f / fmaxf(sqrtf(ss), 1e-12f);
  float4 o0, o1;
  o0.x = v0.x * scale; o0.y = v0.y * scale; o0.z = v0.z * scale; o0.w = v0.w * scale;
  o1.x = v1.x * scale; o1.y = v1.y * scale; o1.z = v1.z * scale; o1.w = v1.w * scale;
  ((float4*)(zout + (size_t)row * SCALE))[lane] = o0;
  ((float4*)(zout + (size_t)row * SCALE))[lane + 64] = o1;
  ushort4 b0, b1;
  b0.x = f2bf(o0.x); b0.y = f2bf(o0.y); b0.z = f2bf(o0.z); b0.w = f2bf(o0.w);
  b1.x = f2bf(o1.x); b1.y = f2bf(o1.y); b1.z = f2bf(o1.z); b1.w = f2bf(o1.w);
  ((ushort4*)(zb + (size_t)row * SCALE))[lane] = b0;
  ((ushort4*)(zb + (size_t)row * SCALE))[lane + 64] = b1;

  // ---- cantor (all lanes redundantly; lane 0 writes) ----
  float s = rd * scale;
  float shift = tanhf(s + b_pos[0]) * 0.3f;
  int max_pos = *gmax + 1;
  float denom = (float)max(max_pos - 1, 1);
  float posf = tclassf[row];
  float x = (max_pos > 1) ? (posf / denom) : posf;
  x = fminf(fmaxf(x, 1e-6f), 1.0f - 1e-6f);
  x = x + shift;
  x = fminf(fmaxf(x, 1e-6f), 1.0f - 1e-6f);

  float alpha = alpha_p[0];
  const float inv = 1.0f / (0.25f + 1e-8f);
  float Cx = 0.0f, w = 0.5f;
  #pragma unroll
  for (int l = 0; l < 12; ++l) {
    float y = x * 3.0f;
    float d0 = y - 0.5f, d1 = y - 1.5f, d2 = y - 2.5f;
    float l0 = -(d0 * d0) * inv, l1 = -(d1 * d1) * inv, l2 = -(d2 * d2) * inv;
    float mx = fmaxf(l0, fmaxf(l1, l2));
    float e0 = __expf(l0 - mx), e1 = __expf(l1 - mx), e2 = __expf(l2 - mx);
    float bit = (e1 * alpha + e2) / (e0 + e1 + e2);
    Cx += bit * w;
    x = y - floorf(y);
    w *= 0.5f;
  }
  if (lane == 0) cv_out[row] = fminf(fmaxf(Cx, 0.0f), 1.0f);
}

// ---------- launch ----------
extern "C" void kernel_launch(void* const* d_in, const int* in_sizes, int n_in,
                              void* d_out, int out_size, void* d_ws, size_t ws_size,
                              hipStream_t stream) {
  const float* features = (const float*)d_in[0];
  const int*   timesteps = (const int*)d_in[1];
  const float* W1 = (const float*)d_in[2];
  const float* b1 = (const float*)d_in[3];
  const float* W2 = (const float*)d_in[4];
  const float* Wt = (const float*)d_in[5];
  const float* bt = (const float*)d_in[6];
  const float* Wp = (const float*)d_in[7];
  const float* bp = (const float*)d_in[8];
  const float* w_pos = (const float*)d_in[9];
  const float* b_pos = (const float*)d_in[10];
  const float* alpha = (const float*)d_in[11];

  char* ws = (char*)d_ws;
  const size_t WS_HB  = (size_t)B_ROWS * SCALE * 4;             // zraw
  const size_t WS_ZB  = WS_HB + (size_t)B_ROWS * BELLY * 2;     // hB
  const size_t WS_W1T = WS_ZB + (size_t)B_ROWS * SCALE * 2;     // zB
  const size_t WS_W2T = WS_W1T + (size_t)BELLY * IN_DIM * 2;
  const size_t WS_WCT = WS_W2T + (size_t)SCALE * BELLY * 2;
  const size_t WS_MAX = WS_WCT + (size_t)1280 * SCALE * 2;      // ~88.9 MB total

  float*          zraw = (float*)(ws);
  unsigned short* hB   = (unsigned short*)(ws + WS_HB);
  unsigned short* zB   = (unsigned short*)(ws + WS_ZB);
  unsigned short* W1T  = (unsigned short*)(ws + WS_W1T);
  unsigned short* W2T  = (unsigned short*)(ws + WS_W2T);
  unsigned short* WCT  = (unsigned short*)(ws + WS_WCT);
  int*            gmax = (int*)(ws + WS_MAX);

  float* out  = (float*)d_out;
  float* o_z  = out;
  float* o_t  = o_z + (size_t)B_ROWS * SCALE;
  float* o_p  = o_t + (size_t)B_ROWS * NBINS;
  float* o_c  = o_p + (size_t)B_ROWS * NPTOT;
  float* o_cv = o_c + B_ROWS;

  hipMemsetAsync(gmax, 0, 4, stream);

  dim3 tb(32, 8);
  transpose_cvt<<<dim3(40, 32), tb, 0, stream>>>(W1, W1T, IN_DIM, BELLY, BELLY);
  transpose_cvt<<<dim3(32, 16), tb, 0, stream>>>(W2, W2T, BELLY, SCALE, SCALE);
  // concat weights: rows 0..1023 = Wp^T (padded), rows 1024..1279 = Wt^T (padded)
  transpose_cvt<<<dim3(16, 32), tb, 0, stream>>>(Wp, WCT, SCALE, NPTOT, 1024);
  transpose_cvt<<<dim3(16, 8),  tb, 0, stream>>>(Wt, WCT + (size_t)1024 * SCALE,
                                                 SCALE, NBINS, 256);

  tclass_kernel<<<64, 256, 0, stream>>>(timesteps, o_c, gmax, B_ROWS);

  // h = relu(features @ W1 + b1) -> bf16   [A = f32 features, fused convert]
  gemm256<IN_DIM, 0, true><<<dim3(B_ROWS / 256, BELLY / 256), 512, 0, stream>>>(
      features, W1T, nullptr, hB, b1, nullptr, nullptr, BELLY);
  // z_raw = h @ W2 -> f32
  gemm256<BELLY, 1, false><<<dim3(B_ROWS / 256, SCALE / 256), 512, 0, stream>>>(
      hB, W2T, zraw, nullptr, nullptr, nullptr, nullptr, SCALE);

  norm_cantor_kernel<<<B_ROWS / 4, 256, 0, stream>>>(
      zraw, o_z, zB, w_pos, b_pos, alpha, o_c, gmax, o_cv);

  // pattern_logits + timestep_logits fused: z @ [Wp | Wt] (N padded to 1280)
  gemm256<SCALE, 2, false><<<dim3(B_ROWS / 256, 5), 512, 0, stream>>>(
      zB, WCT, o_p, nullptr, bp, o_t, bt, NPTOT);
}

// Round 5
// 358.856 us; speedup vs baseline: 1.0775x; 1.0775x over previous
//
#include <hip/hip_runtime.h>
#include <hip/hip_bf16.h>

// Problem constants
#define B_ROWS 16384
#define IN_DIM 1280
#define BELLY  1024
#define SCALE  512
#define NBINS  100
#define NPTOT  1000   // NBINS*NPAT

typedef __attribute__((ext_vector_type(8))) short short8_t;
typedef __attribute__((ext_vector_type(4))) float f32x4;

// ---------- helpers ----------
__device__ __forceinline__ unsigned short f2bf(float f) {
  union { float f; unsigned int u; } v; v.f = f;
  unsigned int r = v.u + 0x7FFFu + ((v.u >> 16) & 1u);  // RNE
  return (unsigned short)(r >> 16);
}

__device__ __forceinline__ void gload16(const void* g, void* l) {
  __builtin_amdgcn_global_load_lds(
      (const __attribute__((address_space(1))) unsigned int*)g,
      (__attribute__((address_space(3))) unsigned int*)l, 16, 0, 0);
}

// ---------- fp32 -> bf16 bulk convert (features) ----------
__global__ void cvt_f32_bf16(const float* __restrict__ in,
                             unsigned short* __restrict__ out, int n4) {
  int i = blockIdx.x * blockDim.x + threadIdx.x;
  int stride = gridDim.x * blockDim.x;
  for (; i < n4; i += stride) {
    float4 v = ((const float4*)in)[i];
    ushort4 o;
    o.x = f2bf(v.x); o.y = f2bf(v.y); o.z = f2bf(v.z); o.w = f2bf(v.w);
    ((ushort4*)out)[i] = o;
  }
}

// ---------- transpose + convert: in f32 [K][N] -> out bf16 [Npad][K], zero-pad rows >= N ----------
__global__ void transpose_cvt(const float* __restrict__ in,
                              unsigned short* __restrict__ out,
                              int K, int N, int Npad) {
  __shared__ float tile[32][33];
  int k0 = blockIdx.x * 32;
  int n0 = blockIdx.y * 32;
  int tx = threadIdx.x, ty = threadIdx.y;  // 32 x 8
  #pragma unroll
  for (int r = 0; r < 32; r += 8) {
    int k = k0 + ty + r, n = n0 + tx;
    tile[ty + r][tx] = (k < K && n < N) ? in[(size_t)k * N + n] : 0.0f;
  }
  __syncthreads();
  #pragma unroll
  for (int r = 0; r < 32; r += 8) {
    int n = n0 + ty + r, k = k0 + tx;
    if (n < Npad && k < K) out[(size_t)n * K + k] = f2bf(tile[tx][ty + r]);
  }
}

// ---------- timestep class + global max ----------
__global__ void tclass_kernel(const int* __restrict__ ts, float* __restrict__ outc,
                              int* __restrict__ gmax, int n) {
  __shared__ int smax;
  if (threadIdx.x == 0) smax = 0;
  __syncthreads();
  int local = 0;
  for (int i = blockIdx.x * blockDim.x + threadIdx.x; i < n;
       i += gridDim.x * blockDim.x) {
    float v = (float)ts[i] / 1000.0f * 100.0f;
    int c = (int)v;
    c = min(max(c, 0), NBINS - 1);
    outc[i] = (float)c;
    local = max(local, c);
  }
  atomicMax(&smax, local);
  __syncthreads();
  if (threadIdx.x == 0) atomicMax(gmax, smax);
}

// ================= 256x256 8-phase GEMM (T2+T3+T4+T5) — round-3 proven =================
// C[M,N] = A[M,K](bf16) * Bt[N,K](bf16)^T. BM=BN=256, BK=64, 8 waves (2Mx4N).
// Both A and B staged via global_load_lds: linear LDS dest + inverse-swizzled
// global source; ds_read with byte ^= (row&7)<<4 slot-XOR (2-way residual = free).
// Counted vmcnt(4) at P4/P8 only — loads stay in flight across barriers.
// EPI 0: +bias, relu -> bf16 outH ; EPI 1: f32 outF ;
// EPI 2: dual-region (fused GEMM3+4): col<1000 -> outF (+bias), col in
//        [1024,1124) -> outF2 (+bias2).
template<int K, int EPI>
__global__ __launch_bounds__(512, 1)
void gemm256(const unsigned short* __restrict__ A,
             const unsigned short* __restrict__ Bt,
             float* __restrict__ outF, unsigned short* __restrict__ outH,
             const float* __restrict__ bias,
             float* __restrict__ outF2, const float* __restrict__ bias2,
             int ldOut) {
  __shared__ __align__(16) unsigned short lds[65536];  // 128 KiB
  constexpr int NT = K / 64;
  static_assert(NT % 2 == 0, "NT must be even");
  const int tid  = threadIdx.x;
  const int wid  = tid >> 6;
  const int lane = tid & 63;
  const int r0 = blockIdx.x * 256;
  const int c0 = blockIdx.y * 256;

  // staging: wave w covers rows [w*16, w*16+16) of a 128-row half;
  // 8 lanes per 64-elem row, col slot pre-swizzled in the GLOBAL source.
  const int srow = wid * 16 + (lane >> 3);
  const int scol = (((lane & 7) ^ (lane >> 3)) << 3);   // elems, inverse-swizzled
  const unsigned short* gA = A  + (size_t)(r0 + srow) * K + scol;
  const unsigned short* gB = Bt + (size_t)(c0 + srow) * K + scol;
  const int sdst = wid * 1024;                          // elem offset of wave chunk

  // fragment read addressing
  const int fr = lane & 15;
  const int Ah = wid >> 2;            // this wave's A half (row block)
  const int wc = (wid & 3) * 64;      // wave col offset in 256-wide tile
  const int ca0 = ((((lane >> 4) << 4) +  0) ^ ((lane & 7) << 4)) >> 1;
  const int ca1 = ((((lane >> 4) << 4) + 64) ^ ((lane & 7) << 4)) >> 1;

  f32x4 acc[8][4] = {};
  short8_t af[4][2];        // A frags: one m-half x 2 k-slices
  short8_t bfr[2][2][2];    // B frags: [nh][nn][ks]

#define STAGE_(buf, mat, half, kt) do {                                        \
    const unsigned short* g_ = ((mat) == 0 ? gA : gB)                          \
        + (size_t)(half) * 128 * K + (size_t)(kt) * 64;                        \
    unsigned short* l_ = &lds[(buf) * 32768 + (mat) * 16384 + (half) * 8192 + sdst]; \
    gload16(g_, l_);                                                           \
    gload16(g_ + 8 * K, l_ + 512);                                             \
  } while (0)

#define LDA_(buf, mh) do {                                                     \
    const unsigned short* ab_ = &lds[(buf) * 32768 + Ah * 8192];               \
    _Pragma("unroll")                                                          \
    for (int mm = 0; mm < 4; ++mm) {                                           \
      int rwh_ = (mh) * 64 + mm * 16 + fr;                                     \
      af[mm][0] = *(const short8_t*)&ab_[rwh_ * 64 + ca0];                     \
      af[mm][1] = *(const short8_t*)&ab_[rwh_ * 64 + ca1];                     \
    } } while (0)

#define LDB_(buf, nh) do {                                                     \
    _Pragma("unroll")                                                          \
    for (int nn = 0; nn < 2; ++nn) {                                           \
      int brow_ = wc + ((nh) * 2 + nn) * 16;                                   \
      const unsigned short* bb_ = &lds[(buf) * 32768 + 16384 + (brow_ >> 7) * 8192]; \
      int rwh_ = (brow_ & 127) + fr;                                           \
      bfr[nh][nn][0] = *(const short8_t*)&bb_[rwh_ * 64 + ca0];                \
      bfr[nh][nn][1] = *(const short8_t*)&bb_[rwh_ * 64 + ca1];                \
    } } while (0)

#define MM_(mh, nh) do {                                                       \
    _Pragma("unroll")                                                          \
    for (int mm = 0; mm < 4; ++mm)                                             \
      _Pragma("unroll")                                                        \
      for (int nn = 0; nn < 2; ++nn) {                                         \
        acc[(mh)*4+mm][(nh)*2+nn] = __builtin_amdgcn_mfma_f32_16x16x32_bf16(   \
            af[mm][0], bfr[nh][nn][0], acc[(mh)*4+mm][(nh)*2+nn], 0, 0, 0);    \
        acc[(mh)*4+mm][(nh)*2+nn] = __builtin_amdgcn_mfma_f32_16x16x32_bf16(   \
            af[mm][1], bfr[nh][nn][1], acc[(mh)*4+mm][(nh)*2+nn], 0, 0, 0);    \
      } } while (0)

#define BAR_       __builtin_amdgcn_s_barrier()
#define LGKM0_     asm volatile("s_waitcnt lgkmcnt(0)")
#define VM4_       asm volatile("s_waitcnt vmcnt(4)" ::: "memory")
#define PRIO1_     __builtin_amdgcn_s_setprio(1)
#define PRIO0_     __builtin_amdgcn_s_setprio(0)

  // ---- prologue: t0 fully + t1.B0,B1 (12 loads/thread); vmcnt(4) -> t0 landed
  STAGE_(0, 1, 0, 0); STAGE_(0, 1, 1, 0);
  STAGE_(0, 0, 0, 0); STAGE_(0, 0, 1, 0);
  STAGE_(1, 1, 0, 1); STAGE_(1, 1, 1, 1);
  VM4_;
  BAR_;

  for (int t = 0; t < NT; t += 2) {
    const int t2 = (t + 2) % NT;       // mod: tail stages garbage, never consumed
    const int t3 = (t + 3) % NT;
    // P1
    LDA_(0, 0); LDB_(0, 0); STAGE_(1, 0, 0, t + 1);
    BAR_; LGKM0_; PRIO1_; MM_(0, 0); PRIO0_; BAR_;
    // P2
    LDB_(0, 1); STAGE_(1, 0, 1, t + 1);
    BAR_; LGKM0_; PRIO1_; MM_(0, 1); PRIO0_; BAR_;
    // P3
    LDA_(0, 1); STAGE_(0, 1, 0, t2);
    BAR_; LGKM0_; PRIO1_; MM_(1, 0); PRIO0_; BAR_;
    // P4
    STAGE_(0, 1, 1, t2); VM4_;
    BAR_; LGKM0_; PRIO1_; MM_(1, 1); PRIO0_; BAR_;
    // P5
    LDA_(1, 0); LDB_(1, 0); STAGE_(0, 0, 0, t2);
    BAR_; LGKM0_; PRIO1_; MM_(0, 0); PRIO0_; BAR_;
    // P6
    LDB_(1, 1); STAGE_(0, 0, 1, t2);
    BAR_; LGKM0_; PRIO1_; MM_(0, 1); PRIO0_; BAR_;
    // P7
    LDA_(1, 1); STAGE_(1, 1, 0, t3);
    BAR_; LGKM0_; PRIO1_; MM_(1, 0); PRIO0_; BAR_;
    // P8
    STAGE_(1, 1, 1, t3); VM4_;
    BAR_; LGKM0_; PRIO1_; MM_(1, 1); PRIO0_; BAR_;
  }

  // drain stray (garbage) gload_lds before this block's LDS could be reused
  asm volatile("s_waitcnt vmcnt(0)" ::: "memory");

  const int orow = (lane >> 4) * 4;
  const int wrr  = (wid >> 2) * 128;
  #pragma unroll
  for (int m = 0; m < 8; ++m) {
    #pragma unroll
    for (int n = 0; n < 4; ++n) {
      #pragma unroll
      for (int i = 0; i < 4; ++i) {
        int row = r0 + wrr + m * 16 + orow + i;
        int col = c0 + wc + n * 16 + fr;
        float v = acc[m][n][i];
        if (EPI == 0) {
          v += bias[col];
          v = fmaxf(v, 0.0f);
          outH[(size_t)row * ldOut + col] = f2bf(v);
        } else if (EPI == 1) {
          outF[(size_t)row * ldOut + col] = v;
        } else {
          if (col < NPTOT) {
            outF[(size_t)row * ldOut + col] = v + bias[col];
          } else if (col >= 1024) {
            int cc = col - 1024;
            if (cc < NBINS) outF2[(size_t)row * NBINS + cc] = v + bias2[cc];
          }
        }
      }
    }
  }
#undef STAGE_
#undef LDA_
#undef LDB_
#undef MM_
}

// ---------- fused row-normalize + cantor ----------
__global__ void norm_cantor_kernel(const float* __restrict__ zraw,
                                   float* __restrict__ zout,
                                   unsigned short* __restrict__ zb,
                                   const float* __restrict__ w_pos,
                                   const float* __restrict__ b_pos,
                                   const float* __restrict__ alpha_p,
                                   const float* __restrict__ tclassf,
                                   const int* __restrict__ gmax,
                                   float* __restrict__ cv_out) {
  int wid = threadIdx.x >> 6, lane = threadIdx.x & 63;
  int row = blockIdx.x * 4 + wid;
  const float4* zr = (const float4*)(zraw + (size_t)row * SCALE);
  const float4* wp = (const float4*)w_pos;
  float4 v0 = zr[lane];
  float4 v1 = zr[lane + 64];
  float4 c0 = wp[lane];
  float4 c1 = wp[lane + 64];
  float ss = v0.x * v0.x + v0.y * v0.y + v0.z * v0.z + v0.w * v0.w
           + v1.x * v1.x + v1.y * v1.y + v1.z * v1.z + v1.w * v1.w;
  float rd = v0.x * c0.x + v0.y * c0.y + v0.z * c0.z + v0.w * c0.w
           + v1.x * c1.x + v1.y * c1.y + v1.z * c1.z + v1.w * c1.w;
  #pragma unroll
  for (int off = 1; off < 64; off <<= 1) {
    ss += __shfl_xor(ss, off);
    rd += __shfl_xor(rd, off);
  }
  float scale = 1.0f / fmaxf(sqrtf(ss), 1e-12f);
  float4 o0, o1;
  o0.x = v0.x * scale; o0.y = v0.y * scale; o0.z = v0.z * scale; o0.w = v0.w * scale;
  o1.x = v1.x * scale; o1.y = v1.y * scale; o1.z = v1.z * scale; o1.w = v1.w * scale;
  ((float4*)(zout + (size_t)row * SCALE))[lane] = o0;
  ((float4*)(zout + (size_t)row * SCALE))[lane + 64] = o1;
  ushort4 b0, b1;
  b0.x = f2bf(o0.x); b0.y = f2bf(o0.y); b0.z = f2bf(o0.z); b0.w = f2bf(o0.w);
  b1.x = f2bf(o1.x); b1.y = f2bf(o1.y); b1.z = f2bf(o1.z); b1.w = f2bf(o1.w);
  ((ushort4*)(zb + (size_t)row * SCALE))[lane] = b0;
  ((ushort4*)(zb + (size_t)row * SCALE))[lane + 64] = b1;

  // ---- cantor (all lanes redundantly; lane 0 writes) ----
  float s = rd * scale;
  float shift = tanhf(s + b_pos[0]) * 0.3f;
  int max_pos = *gmax + 1;
  float denom = (float)max(max_pos - 1, 1);
  float posf = tclassf[row];
  float x = (max_pos > 1) ? (posf / denom) : posf;
  x = fminf(fmaxf(x, 1e-6f), 1.0f - 1e-6f);
  x = x + shift;
  x = fminf(fmaxf(x, 1e-6f), 1.0f - 1e-6f);

  float alpha = alpha_p[0];
  const float inv = 1.0f / (0.25f + 1e-8f);
  float Cx = 0.0f, w = 0.5f;
  #pragma unroll
  for (int l = 0; l < 12; ++l) {
    float y = x * 3.0f;
    float d0 = y - 0.5f, d1 = y - 1.5f, d2 = y - 2.5f;
    float l0 = -(d0 * d0) * inv, l1 = -(d1 * d1) * inv, l2 = -(d2 * d2) * inv;
    float mx = fmaxf(l0, fmaxf(l1, l2));
    float e0 = __expf(l0 - mx), e1 = __expf(l1 - mx), e2 = __expf(l2 - mx);
    float bit = (e1 * alpha + e2) / (e0 + e1 + e2);
    Cx += bit * w;
    x = y - floorf(y);
    w *= 0.5f;
  }
  if (lane == 0) cv_out[row] = fminf(fmaxf(Cx, 0.0f), 1.0f);
}

// ---------- launch ----------
extern "C" void kernel_launch(void* const* d_in, const int* in_sizes, int n_in,
                              void* d_out, int out_size, void* d_ws, size_t ws_size,
                              hipStream_t stream) {
  const float* features = (const float*)d_in[0];
  const int*   timesteps = (const int*)d_in[1];
  const float* W1 = (const float*)d_in[2];
  const float* b1 = (const float*)d_in[3];
  const float* W2 = (const float*)d_in[4];
  const float* Wt = (const float*)d_in[5];
  const float* bt = (const float*)d_in[6];
  const float* Wp = (const float*)d_in[7];
  const float* bp = (const float*)d_in[8];
  const float* w_pos = (const float*)d_in[9];
  const float* b_pos = (const float*)d_in[10];
  const float* alpha = (const float*)d_in[11];

  // ws layout (bytes); featB region (41.9 MB) is reused for zraw (33.5 MB)
  char* ws = (char*)d_ws;
  const size_t WS_H   = (size_t)B_ROWS * IN_DIM * 2;            // featB / zraw
  const size_t WS_ZB  = WS_H + (size_t)B_ROWS * BELLY * 2;      // hB
  const size_t WS_W1T = WS_ZB + (size_t)B_ROWS * SCALE * 2;     // zB
  const size_t WS_W2T = WS_W1T + (size_t)BELLY * IN_DIM * 2;
  const size_t WS_WCT = WS_W2T + (size_t)SCALE * BELLY * 2;
  const size_t WS_MAX = WS_WCT + (size_t)1280 * SCALE * 2;      // ~97.2 MB total

  unsigned short* featB = (unsigned short*)(ws);
  float*          zraw  = (float*)(ws);                  // alias after GEMM1
  unsigned short* hB    = (unsigned short*)(ws + WS_H);
  unsigned short* zB    = (unsigned short*)(ws + WS_ZB);
  unsigned short* W1T   = (unsigned short*)(ws + WS_W1T);
  unsigned short* W2T   = (unsigned short*)(ws + WS_W2T);
  unsigned short* WCT   = (unsigned short*)(ws + WS_WCT);
  int*            gmax  = (int*)(ws + WS_MAX);

  float* out  = (float*)d_out;
  float* o_z  = out;
  float* o_t  = o_z + (size_t)B_ROWS * SCALE;
  float* o_p  = o_t + (size_t)B_ROWS * NBINS;
  float* o_c  = o_p + (size_t)B_ROWS * NPTOT;
  float* o_cv = o_c + B_ROWS;

  hipMemsetAsync(gmax, 0, 4, stream);

  cvt_f32_bf16<<<2048, 256, 0, stream>>>(features, featB, B_ROWS * IN_DIM / 4);

  dim3 tb(32, 8);
  transpose_cvt<<<dim3(40, 32), tb, 0, stream>>>(W1, W1T, IN_DIM, BELLY, BELLY);
  transpose_cvt<<<dim3(32, 16), tb, 0, stream>>>(W2, W2T, BELLY, SCALE, SCALE);
  // concat weights: rows 0..1023 = Wp^T (padded), rows 1024..1279 = Wt^T (padded)
  transpose_cvt<<<dim3(16, 32), tb, 0, stream>>>(Wp, WCT, SCALE, NPTOT, 1024);
  transpose_cvt<<<dim3(16, 8),  tb, 0, stream>>>(Wt, WCT + (size_t)1024 * SCALE,
                                                 SCALE, NBINS, 256);

  tclass_kernel<<<64, 256, 0, stream>>>(timesteps, o_c, gmax, B_ROWS);

  // h = relu(features @ W1 + b1) -> bf16
  gemm256<IN_DIM, 0><<<dim3(B_ROWS / 256, BELLY / 256), 512, 0, stream>>>(
      featB, W1T, nullptr, hB, b1, nullptr, nullptr, BELLY);
  // z_raw = h @ W2 -> f32
  gemm256<BELLY, 1><<<dim3(B_ROWS / 256, SCALE / 256), 512, 0, stream>>>(
      hB, W2T, zraw, nullptr, nullptr, nullptr, nullptr, SCALE);

  norm_cantor_kernel<<<B_ROWS / 4, 256, 0, stream>>>(
      zraw, o_z, zB, w_pos, b_pos, alpha, o_c, gmax, o_cv);

  // pattern_logits + timestep_logits fused: z @ [Wp | Wt] (N padded to 1280)
  gemm256<SCALE, 2><<<dim3(B_ROWS / 256, 5), 512, 0, stream>>>(
      zB, WCT, o_p, nullptr, bp, o_t, bt, NPTOT);
}

// Round 6
// 346.644 us; speedup vs baseline: 1.1155x; 1.0352x over previous
//
#include <hip/hip_runtime.h>
#include <hip/hip_bf16.h>

// Problem constants
#define B_ROWS 16384
#define IN_DIM 1280
#define BELLY  1024
#define SCALE  512
#define NBINS  100
#define NPTOT  1000   // NBINS*NPAT

typedef __attribute__((ext_vector_type(8))) short short8_t;
typedef __attribute__((ext_vector_type(4))) float f32x4;

// ---------- helpers ----------
__device__ __forceinline__ unsigned short f2bf(float f) {
  union { float f; unsigned int u; } v; v.f = f;
  unsigned int r = v.u + 0x7FFFu + ((v.u >> 16) & 1u);  // RNE
  return (unsigned short)(r >> 16);
}

__device__ __forceinline__ void gload16(const void* g, void* l) {
  __builtin_amdgcn_global_load_lds(
      (const __attribute__((address_space(1))) unsigned int*)g,
      (__attribute__((address_space(3))) unsigned int*)l, 16, 0, 0);
}

// ---------- fp32 -> bf16 bulk convert (features) ----------
__global__ void cvt_f32_bf16(const float* __restrict__ in,
                             unsigned short* __restrict__ out, int n4) {
  int i = blockIdx.x * blockDim.x + threadIdx.x;
  int stride = gridDim.x * blockDim.x;
  for (; i < n4; i += stride) {
    float4 v = ((const float4*)in)[i];
    ushort4 o;
    o.x = f2bf(v.x); o.y = f2bf(v.y); o.z = f2bf(v.z); o.w = f2bf(v.w);
    ((ushort4*)out)[i] = o;
  }
}

// ---------- transpose + convert: in f32 [K][N] -> out bf16 [Npad][K], zero-pad rows >= N ----------
__global__ void transpose_cvt(const float* __restrict__ in,
                              unsigned short* __restrict__ out,
                              int K, int N, int Npad) {
  __shared__ float tile[32][33];
  int k0 = blockIdx.x * 32;
  int n0 = blockIdx.y * 32;
  int tx = threadIdx.x, ty = threadIdx.y;  // 32 x 8
  #pragma unroll
  for (int r = 0; r < 32; r += 8) {
    int k = k0 + ty + r, n = n0 + tx;
    tile[ty + r][tx] = (k < K && n < N) ? in[(size_t)k * N + n] : 0.0f;
  }
  __syncthreads();
  #pragma unroll
  for (int r = 0; r < 32; r += 8) {
    int n = n0 + ty + r, k = k0 + tx;
    if (n < Npad && k < K) out[(size_t)n * K + k] = f2bf(tile[tx][ty + r]);
  }
}

// ---------- timestep class + global max ----------
__global__ void tclass_kernel(const int* __restrict__ ts, float* __restrict__ outc,
                              int* __restrict__ gmax, int n) {
  __shared__ int smax;
  if (threadIdx.x == 0) smax = 0;
  __syncthreads();
  int local = 0;
  for (int i = blockIdx.x * blockDim.x + threadIdx.x; i < n;
       i += gridDim.x * blockDim.x) {
    float v = (float)ts[i] / 1000.0f * 100.0f;
    int c = (int)v;
    c = min(max(c, 0), NBINS - 1);
    outc[i] = (float)c;
    local = max(local, c);
  }
  atomicMax(&smax, local);
  __syncthreads();
  if (threadIdx.x == 0) atomicMax(gmax, smax);
}

// ================= 256x256 8-phase GEMM (T2+T3+T4+T5) — GEMM1 only =================
// Proven round-3/5. Used where grid = 256 blocks (perfect balance) and K is long.
// EPI 0: +bias, relu -> bf16 outH.
template<int K, int EPI>
__global__ __launch_bounds__(512, 1)
void gemm256(const unsigned short* __restrict__ A,
             const unsigned short* __restrict__ Bt,
             float* __restrict__ outF, unsigned short* __restrict__ outH,
             const float* __restrict__ bias, int ldOut) {
  __shared__ __align__(16) unsigned short lds[65536];  // 128 KiB
  constexpr int NT = K / 64;
  static_assert(NT % 2 == 0, "NT must be even");
  const int tid  = threadIdx.x;
  const int wid  = tid >> 6;
  const int lane = tid & 63;
  const int r0 = blockIdx.x * 256;
  const int c0 = blockIdx.y * 256;

  const int srow = wid * 16 + (lane >> 3);
  const int scol = (((lane & 7) ^ (lane >> 3)) << 3);   // elems, inverse-swizzled
  const unsigned short* gA = A  + (size_t)(r0 + srow) * K + scol;
  const unsigned short* gB = Bt + (size_t)(c0 + srow) * K + scol;
  const int sdst = wid * 1024;

  const int fr = lane & 15;
  const int Ah = wid >> 2;
  const int wc = (wid & 3) * 64;
  const int ca0 = ((((lane >> 4) << 4) +  0) ^ ((lane & 7) << 4)) >> 1;
  const int ca1 = ((((lane >> 4) << 4) + 64) ^ ((lane & 7) << 4)) >> 1;

  f32x4 acc[8][4] = {};
  short8_t af[4][2];
  short8_t bfr[2][2][2];

#define STAGE_(buf, mat, half, kt) do {                                        \
    const unsigned short* g_ = ((mat) == 0 ? gA : gB)                          \
        + (size_t)(half) * 128 * K + (size_t)(kt) * 64;                        \
    unsigned short* l_ = &lds[(buf) * 32768 + (mat) * 16384 + (half) * 8192 + sdst]; \
    gload16(g_, l_);                                                           \
    gload16(g_ + 8 * K, l_ + 512);                                             \
  } while (0)

#define LDA_(buf, mh) do {                                                     \
    const unsigned short* ab_ = &lds[(buf) * 32768 + Ah * 8192];               \
    _Pragma("unroll")                                                          \
    for (int mm = 0; mm < 4; ++mm) {                                           \
      int rwh_ = (mh) * 64 + mm * 16 + fr;                                     \
      af[mm][0] = *(const short8_t*)&ab_[rwh_ * 64 + ca0];                     \
      af[mm][1] = *(const short8_t*)&ab_[rwh_ * 64 + ca1];                     \
    } } while (0)

#define LDB_(buf, nh) do {                                                     \
    _Pragma("unroll")                                                          \
    for (int nn = 0; nn < 2; ++nn) {                                           \
      int brow_ = wc + ((nh) * 2 + nn) * 16;                                   \
      const unsigned short* bb_ = &lds[(buf) * 32768 + 16384 + (brow_ >> 7) * 8192]; \
      int rwh_ = (brow_ & 127) + fr;                                           \
      bfr[nh][nn][0] = *(const short8_t*)&bb_[rwh_ * 64 + ca0];                \
      bfr[nh][nn][1] = *(const short8_t*)&bb_[rwh_ * 64 + ca1];                \
    } } while (0)

#define MM_(mh, nh) do {                                                       \
    _Pragma("unroll")                                                          \
    for (int mm = 0; mm < 4; ++mm)                                             \
      _Pragma("unroll")                                                        \
      for (int nn = 0; nn < 2; ++nn) {                                         \
        acc[(mh)*4+mm][(nh)*2+nn] = __builtin_amdgcn_mfma_f32_16x16x32_bf16(   \
            af[mm][0], bfr[nh][nn][0], acc[(mh)*4+mm][(nh)*2+nn], 0, 0, 0);    \
        acc[(mh)*4+mm][(nh)*2+nn] = __builtin_amdgcn_mfma_f32_16x16x32_bf16(   \
            af[mm][1], bfr[nh][nn][1], acc[(mh)*4+mm][(nh)*2+nn], 0, 0, 0);    \
      } } while (0)

#define BAR_       __builtin_amdgcn_s_barrier()
#define LGKM0_     asm volatile("s_waitcnt lgkmcnt(0)")
#define VM4_       asm volatile("s_waitcnt vmcnt(4)" ::: "memory")
#define PRIO1_     __builtin_amdgcn_s_setprio(1)
#define PRIO0_     __builtin_amdgcn_s_setprio(0)

  STAGE_(0, 1, 0, 0); STAGE_(0, 1, 1, 0);
  STAGE_(0, 0, 0, 0); STAGE_(0, 0, 1, 0);
  STAGE_(1, 1, 0, 1); STAGE_(1, 1, 1, 1);
  VM4_;
  BAR_;

  for (int t = 0; t < NT; t += 2) {
    const int t2 = (t + 2) % NT;
    const int t3 = (t + 3) % NT;
    LDA_(0, 0); LDB_(0, 0); STAGE_(1, 0, 0, t + 1);
    BAR_; LGKM0_; PRIO1_; MM_(0, 0); PRIO0_; BAR_;
    LDB_(0, 1); STAGE_(1, 0, 1, t + 1);
    BAR_; LGKM0_; PRIO1_; MM_(0, 1); PRIO0_; BAR_;
    LDA_(0, 1); STAGE_(0, 1, 0, t2);
    BAR_; LGKM0_; PRIO1_; MM_(1, 0); PRIO0_; BAR_;
    STAGE_(0, 1, 1, t2); VM4_;
    BAR_; LGKM0_; PRIO1_; MM_(1, 1); PRIO0_; BAR_;
    LDA_(1, 0); LDB_(1, 0); STAGE_(0, 0, 0, t2);
    BAR_; LGKM0_; PRIO1_; MM_(0, 0); PRIO0_; BAR_;
    LDB_(1, 1); STAGE_(0, 0, 1, t2);
    BAR_; LGKM0_; PRIO1_; MM_(0, 1); PRIO0_; BAR_;
    LDA_(1, 1); STAGE_(1, 1, 0, t3);
    BAR_; LGKM0_; PRIO1_; MM_(1, 0); PRIO0_; BAR_;
    STAGE_(1, 1, 1, t3); VM4_;
    BAR_; LGKM0_; PRIO1_; MM_(1, 1); PRIO0_; BAR_;
  }

  asm volatile("s_waitcnt vmcnt(0)" ::: "memory");

  const int orow = (lane >> 4) * 4;
  const int wrr  = (wid >> 2) * 128;
  #pragma unroll
  for (int m = 0; m < 8; ++m) {
    #pragma unroll
    for (int n = 0; n < 4; ++n) {
      #pragma unroll
      for (int i = 0; i < 4; ++i) {
        int row = r0 + wrr + m * 16 + orow + i;
        int col = c0 + wc + n * 16 + fr;
        float v = acc[m][n][i];
        if (EPI == 0) {
          v += bias[col];
          v = fmaxf(v, 0.0f);
          outH[(size_t)row * ldOut + col] = f2bf(v);
        } else {
          outF[(size_t)row * ldOut + col] = v;
        }
      }
    }
  }
#undef STAGE_
#undef LDA_
#undef LDB_
#undef MM_
}

// ---------- 128x128 m97-structure GEMM (r2-proven, 586 TF class) ----------
// 16 KiB LDS -> 3+ blocks/CU; good for short-K / odd-grid GEMMs (no tail).
// EPI 1: f32 store. EPI 2: dual-region (fused GEMM3+4): col<1000 -> outF (+bias);
// col in [1024,1124) -> outF2 (+bias2); else dropped.
template<int K, int EPI>
__global__ __launch_bounds__(256)
void gemm128(const unsigned short* __restrict__ A,
             const unsigned short* __restrict__ Bt,
             float* __restrict__ outF, const float* __restrict__ bias,
             float* __restrict__ outF2, const float* __restrict__ bias2,
             int ldOut) {
  __shared__ __align__(16) unsigned short As[128 * 32];
  __shared__ __align__(16) unsigned short Bs[128 * 32];

  const int tid  = threadIdx.x;
  const int wid  = tid >> 6;
  const int lane = tid & 63;
  const int r0 = blockIdx.x * 128;
  const int c0 = blockIdx.y * 128;

  const int arow = lane >> 2;
  const int acol = (lane & 3) * 8;
  const unsigned short* gA0 = A  + (size_t)(r0 + 16 * (2 * wid + 0) + arow) * K + acol;
  const unsigned short* gA1 = A  + (size_t)(r0 + 16 * (2 * wid + 1) + arow) * K + acol;
  const unsigned short* gB0 = Bt + (size_t)(c0 + 16 * (2 * wid + 0) + arow) * K + acol;
  const unsigned short* gB1 = Bt + (size_t)(c0 + 16 * (2 * wid + 1) + arow) * K + acol;
  unsigned short* lA0 = &As[(2 * wid + 0) * 512];
  unsigned short* lA1 = &As[(2 * wid + 1) * 512];
  unsigned short* lB0 = &Bs[(2 * wid + 0) * 512];
  unsigned short* lB1 = &Bs[(2 * wid + 1) * 512];

  const int wr   = (wid >> 1) * 64;
  const int wc   = (wid & 1) * 64;
  const int fr   = lane & 15;
  const int koff = (lane >> 4) * 8;

  f32x4 acc[4][4] = {};

  for (int k0 = 0; k0 < K; k0 += 32) {
    gload16(gA0 + k0, lA0);
    gload16(gA1 + k0, lA1);
    gload16(gB0 + k0, lB0);
    gload16(gB1 + k0, lB1);
    __syncthreads();

    short8_t af[4], bfr[4];
    #pragma unroll
    for (int m = 0; m < 4; ++m)
      af[m] = *(const short8_t*)&As[(wr + m * 16 + fr) * 32 + koff];
    #pragma unroll
    for (int n = 0; n < 4; ++n)
      bfr[n] = *(const short8_t*)&Bs[(wc + n * 16 + fr) * 32 + koff];

    #pragma unroll
    for (int m = 0; m < 4; ++m)
      #pragma unroll
      for (int n = 0; n < 4; ++n)
        acc[m][n] = __builtin_amdgcn_mfma_f32_16x16x32_bf16(af[m], bfr[n], acc[m][n], 0, 0, 0);

    __syncthreads();
  }

  const int orow = (lane >> 4) * 4;
  #pragma unroll
  for (int m = 0; m < 4; ++m) {
    #pragma unroll
    for (int n = 0; n < 4; ++n) {
      #pragma unroll
      for (int i = 0; i < 4; ++i) {
        int row = r0 + wr + m * 16 + orow + i;
        int col = c0 + wc + n * 16 + fr;
        float v = acc[m][n][i];
        if (EPI == 1) {
          outF[(size_t)row * ldOut + col] = v;
        } else {
          if (col < NPTOT) {
            outF[(size_t)row * ldOut + col] = v + bias[col];
          } else if (col >= 1024) {
            int cc = col - 1024;
            if (cc < NBINS) outF2[(size_t)row * NBINS + cc] = v + bias2[cc];
          }
        }
      }
    }
  }
}

// ---------- fused row-normalize + cantor ----------
__global__ void norm_cantor_kernel(const float* __restrict__ zraw,
                                   float* __restrict__ zout,
                                   unsigned short* __restrict__ zb,
                                   const float* __restrict__ w_pos,
                                   const float* __restrict__ b_pos,
                                   const float* __restrict__ alpha_p,
                                   const float* __restrict__ tclassf,
                                   const int* __restrict__ gmax,
                                   float* __restrict__ cv_out) {
  int wid = threadIdx.x >> 6, lane = threadIdx.x & 63;
  int row = blockIdx.x * 4 + wid;
  const float4* zr = (const float4*)(zraw + (size_t)row * SCALE);
  const float4* wp = (const float4*)w_pos;
  float4 v0 = zr[lane];
  float4 v1 = zr[lane + 64];
  float4 c0 = wp[lane];
  float4 c1 = wp[lane + 64];
  float ss = v0.x * v0.x + v0.y * v0.y + v0.z * v0.z + v0.w * v0.w
           + v1.x * v1.x + v1.y * v1.y + v1.z * v1.z + v1.w * v1.w;
  float rd = v0.x * c0.x + v0.y * c0.y + v0.z * c0.z + v0.w * c0.w
           + v1.x * c1.x + v1.y * c1.y + v1.z * c1.z + v1.w * c1.w;
  #pragma unroll
  for (int off = 1; off < 64; off <<= 1) {
    ss += __shfl_xor(ss, off);
    rd += __shfl_xor(rd, off);
  }
  float scale = 1.0f / fmaxf(sqrtf(ss), 1e-12f);
  float4 o0, o1;
  o0.x = v0.x * scale; o0.y = v0.y * scale; o0.z = v0.z * scale; o0.w = v0.w * scale;
  o1.x = v1.x * scale; o1.y = v1.y * scale; o1.z = v1.z * scale; o1.w = v1.w * scale;
  ((float4*)(zout + (size_t)row * SCALE))[lane] = o0;
  ((float4*)(zout + (size_t)row * SCALE))[lane + 64] = o1;
  ushort4 b0, b1;
  b0.x = f2bf(o0.x); b0.y = f2bf(o0.y); b0.z = f2bf(o0.z); b0.w = f2bf(o0.w);
  b1.x = f2bf(o1.x); b1.y = f2bf(o1.y); b1.z = f2bf(o1.z); b1.w = f2bf(o1.w);
  ((ushort4*)(zb + (size_t)row * SCALE))[lane] = b0;
  ((ushort4*)(zb + (size_t)row * SCALE))[lane + 64] = b1;

  // ---- cantor (all lanes redundantly; lane 0 writes) ----
  float s = rd * scale;
  float shift = tanhf(s + b_pos[0]) * 0.3f;
  int max_pos = *gmax + 1;
  float denom = (float)max(max_pos - 1, 1);
  float posf = tclassf[row];
  float x = (max_pos > 1) ? (posf / denom) : posf;
  x = fminf(fmaxf(x, 1e-6f), 1.0f - 1e-6f);
  x = x + shift;
  x = fminf(fmaxf(x, 1e-6f), 1.0f - 1e-6f);

  float alpha = alpha_p[0];
  const float inv = 1.0f / (0.25f + 1e-8f);
  float Cx = 0.0f, w = 0.5f;
  #pragma unroll
  for (int l = 0; l < 12; ++l) {
    float y = x * 3.0f;
    float d0 = y - 0.5f, d1 = y - 1.5f, d2 = y - 2.5f;
    float l0 = -(d0 * d0) * inv, l1 = -(d1 * d1) * inv, l2 = -(d2 * d2) * inv;
    float mx = fmaxf(l0, fmaxf(l1, l2));
    float e0 = __expf(l0 - mx), e1 = __expf(l1 - mx), e2 = __expf(l2 - mx);
    float bit = (e1 * alpha + e2) / (e0 + e1 + e2);
    Cx += bit * w;
    x = y - floorf(y);
    w *= 0.5f;
  }
  if (lane == 0) cv_out[row] = fminf(fmaxf(Cx, 0.0f), 1.0f);
}

// ---------- launch ----------
extern "C" void kernel_launch(void* const* d_in, const int* in_sizes, int n_in,
                              void* d_out, int out_size, void* d_ws, size_t ws_size,
                              hipStream_t stream) {
  const float* features = (const float*)d_in[0];
  const int*   timesteps = (const int*)d_in[1];
  const float* W1 = (const float*)d_in[2];
  const float* b1 = (const float*)d_in[3];
  const float* W2 = (const float*)d_in[4];
  const float* Wt = (const float*)d_in[5];
  const float* bt = (const float*)d_in[6];
  const float* Wp = (const float*)d_in[7];
  const float* bp = (const float*)d_in[8];
  const float* w_pos = (const float*)d_in[9];
  const float* b_pos = (const float*)d_in[10];
  const float* alpha = (const float*)d_in[11];

  // ws layout (bytes); featB region (41.9 MB) is reused for zraw (33.5 MB)
  char* ws = (char*)d_ws;
  const size_t WS_H   = (size_t)B_ROWS * IN_DIM * 2;            // featB / zraw
  const size_t WS_ZB  = WS_H + (size_t)B_ROWS * BELLY * 2;      // hB
  const size_t WS_W1T = WS_ZB + (size_t)B_ROWS * SCALE * 2;     // zB
  const size_t WS_W2T = WS_W1T + (size_t)BELLY * IN_DIM * 2;
  const size_t WS_WCT = WS_W2T + (size_t)SCALE * BELLY * 2;
  const size_t WS_MAX = WS_WCT + (size_t)1280 * SCALE * 2;      // ~97.2 MB total

  unsigned short* featB = (unsigned short*)(ws);
  float*          zraw  = (float*)(ws);                  // alias after GEMM1
  unsigned short* hB    = (unsigned short*)(ws + WS_H);
  unsigned short* zB    = (unsigned short*)(ws + WS_ZB);
  unsigned short* W1T   = (unsigned short*)(ws + WS_W1T);
  unsigned short* W2T   = (unsigned short*)(ws + WS_W2T);
  unsigned short* WCT   = (unsigned short*)(ws + WS_WCT);
  int*            gmax  = (int*)(ws + WS_MAX);

  float* out  = (float*)d_out;
  float* o_z  = out;
  float* o_t  = o_z + (size_t)B_ROWS * SCALE;
  float* o_p  = o_t + (size_t)B_ROWS * NBINS;
  float* o_c  = o_p + (size_t)B_ROWS * NPTOT;
  float* o_cv = o_c + B_ROWS;

  hipMemsetAsync(gmax, 0, 4, stream);

  cvt_f32_bf16<<<2048, 256, 0, stream>>>(features, featB, B_ROWS * IN_DIM / 4);

  dim3 tb(32, 8);
  transpose_cvt<<<dim3(40, 32), tb, 0, stream>>>(W1, W1T, IN_DIM, BELLY, BELLY);
  transpose_cvt<<<dim3(32, 16), tb, 0, stream>>>(W2, W2T, BELLY, SCALE, SCALE);
  // concat weights: rows 0..1023 = Wp^T (padded), rows 1024..1151 = Wt^T (padded to 128)
  transpose_cvt<<<dim3(16, 32), tb, 0, stream>>>(Wp, WCT, SCALE, NPTOT, 1024);
  transpose_cvt<<<dim3(16, 4),  tb, 0, stream>>>(Wt, WCT + (size_t)1024 * SCALE,
                                                 SCALE, NBINS, 128);

  tclass_kernel<<<64, 256, 0, stream>>>(timesteps, o_c, gmax, B_ROWS);

  // h = relu(features @ W1 + b1) -> bf16   [256^2 8-phase, grid 256 = balanced]
  gemm256<IN_DIM, 0><<<dim3(B_ROWS / 256, BELLY / 256), 512, 0, stream>>>(
      featB, W1T, nullptr, hB, b1, BELLY);
  // z_raw = h @ W2 -> f32                   [128^2, grid 512 = no idle CUs]
  gemm128<BELLY, 1><<<dim3(B_ROWS / 128, SCALE / 128), 256, 0, stream>>>(
      hB, W2T, zraw, nullptr, nullptr, nullptr, SCALE);

  norm_cantor_kernel<<<B_ROWS / 4, 256, 0, stream>>>(
      zraw, o_z, zB, w_pos, b_pos, alpha, o_c, gmax, o_cv);

  // pattern+timestep logits fused: z @ [Wp | Wt]  [128^2, grid (128,9)=1152 blocks]
  gemm128<SCALE, 2><<<dim3(B_ROWS / 128, 9), 256, 0, stream>>>(
      zB, WCT, o_p, bp, o_t, bt, NPTOT);
}